// Round 6
// baseline (1048.132 us; speedup 1.0000x reference)
//
#include <hip/hip_runtime.h>
#include <hip/hip_bf16.h>
#include <math.h>

// FlexBertGLUMoE: S=8192 tokens, H=1024, E=8, K=2, F=2048, C=2560
#define S_TOK 8192
#define HDIM  1024
#define FDIM  2048
#define CAP   2560

typedef unsigned short u16;
typedef short  s16x8 __attribute__((ext_vector_type(8)));   // 8 bf16 in 4 VGPRs
typedef float  f32x4 __attribute__((ext_vector_type(4)));

__device__ __forceinline__ u16 f2b(float f){
  unsigned u = __builtin_bit_cast(unsigned, f);
  u = (u + 0x7FFFu + ((u >> 16) & 1u)) >> 16;   // RNE
  return (u16)u;
}
__device__ __forceinline__ float b2f(u16 h){
  unsigned u = ((unsigned)h) << 16;
  return __builtin_bit_cast(float, u);
}
__device__ __forceinline__ void gl_lds16(const u16* g, u16* l){
  // async global->LDS, 16B per lane; LDS dest = wave-uniform base + lane*16
  auto gp = (const __attribute__((address_space(1))) unsigned int*)g;
  auto lp = (__attribute__((address_space(3))) unsigned int*)l;
  __builtin_amdgcn_global_load_lds(gp, lp, 16, 0, 0);
}
// packed f32x2 -> bf16x2 (RNE), lo = first arg  [HW: gfx950, learn_hip m214]
__device__ __forceinline__ unsigned pkbf(float a, float b){
  unsigned d;
  asm("v_cvt_pk_bf16_f32 %0, %1, %2" : "=v"(d) : "v"(a), "v"(b));
  return d;
}
__device__ __forceinline__ float f4get(const float4& v, int i){
  return ((const float*)&v)[i];
}
// tanh-GELU: max |delta| vs exact erf-GELU ~3e-4, invisible under bf16 rounding
__device__ __forceinline__ float gelu_t(float a){
  float z = 0.7978845608f * a * (1.f + 0.044715f * a * a);
  float e = __expf(-2.f * fabsf(z));
  float th = (1.f - e) / (1.f + e);
  th = (z < 0.f) ? -th : th;
  return 0.5f * a * (1.f + th);
}

// ---------------- gating: fp64 logits (ranking must match np ref), softmax, top-2
__global__ __launch_bounds__(256) void k_gating(const float* __restrict__ x,
                                                const float* __restrict__ Wg,
                                                int* __restrict__ eidx, float* __restrict__ vals){
  int t = threadIdx.x, wid = t >> 6, l = t & 63;
  int s = blockIdx.x * 4 + wid;
  const float4* xr = (const float4*)(x + (size_t)s * HDIM);
  const float4* wg = (const float4*)Wg;
  double acc[8] = {0,0,0,0,0,0,0,0};
  #pragma unroll
  for (int j4 = 0; j4 < 4; j4++){
    float4 xv = xr[l * 4 + j4];
    float xa[4] = {xv.x, xv.y, xv.z, xv.w};
    #pragma unroll
    for (int q = 0; q < 4; q++){
      int h = l * 16 + j4 * 4 + q;
      float4 w0 = wg[h * 2], w1 = wg[h * 2 + 1];
      double xd = (double)xa[q];
      acc[0] += xd * w0.x; acc[1] += xd * w0.y; acc[2] += xd * w0.z; acc[3] += xd * w0.w;
      acc[4] += xd * w1.x; acc[5] += xd * w1.y; acc[6] += xd * w1.z; acc[7] += xd * w1.w;
    }
  }
  #pragma unroll
  for (int off = 32; off; off >>= 1)
    #pragma unroll
    for (int e = 0; e < 8; e++) acc[e] += __shfl_down(acc[e], off);
  if (l == 0){
    double mx = acc[0];
    #pragma unroll
    for (int e = 1; e < 8; e++) mx = acc[e] > mx ? acc[e] : mx;
    double ex[8], sum = 0.0;
    #pragma unroll
    for (int e = 0; e < 8; e++){ ex[e] = exp(acc[e] - mx); sum += ex[e]; }
    double inv = 1.0 / sum;
    double p0 = -1.0; int e0 = 0;
    #pragma unroll
    for (int e = 0; e < 8; e++){ double p = ex[e] * inv; if (p > p0){ p0 = p; e0 = e; } }
    double p1 = -1.0; int e1 = 0;
    #pragma unroll
    for (int e = 0; e < 8; e++){ double p = ex[e] * inv; if (e != e0 && p > p1){ p1 = p; e1 = e; } }
    eidx[s] = e0;          vals[s] = (float)p0;
    eidx[S_TOK + s] = e1;  vals[S_TOK + s] = (float)p1;
  }
}

// ---------------- capacity scan (flat order i = k*S + s), slots, gates, counts
__global__ __launch_bounds__(1024) void k_scan(const int* __restrict__ eidx,
                                               const float* __restrict__ vals,
                                               int* __restrict__ slot, float* __restrict__ gates,
                                               int* __restrict__ cnt){
  __shared__ int wavetot[16][9];
  __shared__ int waveoff[16][9];
  __shared__ unsigned char keepb[2 * S_TOK];
  int t = threadIdx.x, w = t >> 6, l = t & 63;
  int le[16];
  int c[8] = {0,0,0,0,0,0,0,0};
  #pragma unroll
  for (int j = 0; j < 16; j++){ int e = eidx[t * 16 + j]; le[j] = e; c[e]++; }
  int inc[8];
  #pragma unroll
  for (int e = 0; e < 8; e++) inc[e] = c[e];
  #pragma unroll
  for (int off = 1; off < 64; off <<= 1)
    #pragma unroll
    for (int e = 0; e < 8; e++){
      int v = __shfl_up(inc[e], off);
      if (l >= off) inc[e] += v;
    }
  if (l == 63)
    #pragma unroll
    for (int e = 0; e < 8; e++) wavetot[w][e] = inc[e];
  __syncthreads();
  if (t < 8){
    int run = 0;
    for (int ww = 0; ww < 16; ww++){ waveoff[ww][t] = run; run += wavetot[ww][t]; }
    cnt[t] = min(run, CAP);
  }
  __syncthreads();
  int run[8];
  #pragma unroll
  for (int e = 0; e < 8; e++) run[e] = waveoff[w][e] + (inc[e] - c[e]);
  #pragma unroll
  for (int j = 0; j < 16; j++){
    int i = t * 16 + j; int e = le[j]; int loc = run[e]++;
    int kp = (loc < CAP);
    keepb[i] = (unsigned char)kp;
    slot[i] = kp ? (e * CAP + loc) : -1;
  }
  __syncthreads();
  #pragma unroll
  for (int r = 0; r < 8; r++){
    int s = t + 1024 * r;
    float g0 = keepb[s]         ? vals[s]         : 0.f;
    float g1 = keepb[S_TOK + s] ? vals[S_TOK + s] : 0.f;
    float inv = 1.f / fmaxf(g0 + g1, 1e-9f);
    gates[s] = g0 * inv;
    gates[S_TOK + s] = g1 * inv;
  }
}

// ---------------- scatter kept tokens into expert buffers (f32 -> bf16)
__global__ __launch_bounds__(256) void k_scatter(const float* __restrict__ x,
                                                 const int* __restrict__ slot,
                                                 u16* __restrict__ A){
  int i = blockIdx.x;
  int sl = slot[i];
  if (sl < 0) return;
  int s = i & (S_TOK - 1);
  int t = threadIdx.x;
  float4 v = ((const float4*)(x + (size_t)s * HDIM))[t];
  ushort4 o; o.x = f2b(v.x); o.y = f2b(v.y); o.z = f2b(v.z); o.w = f2b(v.w);
  ((ushort4*)(A + (size_t)sl * HDIM))[t] = o;
}

// ================= 256x256 8-phase GEMM, fused B transpose+cast =================
// A [E][CAP][LDK] bf16 row-major (gload_lds staged, T2-swizzled LDS).
// B read DIRECTLY from f32 weights [E][LDK][NSRC] (K-major): per-thread 4x4
// block load -> in-reg transpose -> cvt_pk bf16 -> swizzled ds_write_b64 (T14).
// vmcnt ledger: 4 B0f + 4 B1f + 4 A gload per tile, uniform vmcnt(8) steady.
// T1 bijective XCD remap; T2 XOR-swizzle (granule 8 u16); T5 setprio.

#define STAGE_A(h, tt, par) { \
    const u16* gp_ = Ap + (size_t)((h)*128 + c0*8) * LDK + (size_t)(tt) * 64 + srow_off; \
    u16* lp_ = lds + (par)*16384 + (h)*8192 + c0*512; \
    gl_lds16(gp_, lp_); gl_lds16(gp_ + (size_t)8*LDK, lp_ + 512); }

#define LOADB(R, h, tt) { \
    const float* gp_ = Bsrc_e + (size_t)((tt)*64 + kl) * NSRC + colh[h]; \
    R[0] = *(const float4*)gp_;             R[1] = *(const float4*)(gp_ + NSRC); \
    R[2] = *(const float4*)(gp_ + 2*NSRC);  R[3] = *(const float4*)(gp_ + 3*NSRC); }

#define WRITEB(R, h, par) { \
    _Pragma("unroll") \
    for (int i_ = 0; i_ < 4; ++i_){ \
      int row_ = (h)*128 + nl0 + i_; \
      int ad_  = 32768 + (par)*16384 + row_*64 + (kl ^ ((row_ & 7) * 8)); \
      uint2 d_; \
      d_.x = pkbf(f4get(R[0], i_), f4get(R[1], i_)); \
      d_.y = pkbf(f4get(R[2], i_), f4get(R[3], i_)); \
      *(uint2*)&lds[ad_] = d_; \
    } }

#define CFENCE asm volatile("" ::: "memory");
#define VM8 asm volatile("s_waitcnt vmcnt(8)" ::: "memory");
#define VM4 asm volatile("s_waitcnt vmcnt(4)" ::: "memory");
#define VM0 asm volatile("s_waitcnt vmcnt(0)" ::: "memory");
#define LGKM0 asm volatile("s_waitcnt lgkmcnt(0)" ::: "memory");

#define PHASE(P, KSW, NH, PRE, POST) { \
    if ((NH) == 0) { \
      _Pragma("unroll") \
      for (int m_ = 0; m_ < 8; ++m_) \
        af[m_] = *(const s16x8*)&lds[(P)*16384 + aoff + m_*1024 + (KSW)]; \
    } \
    bf[0] = *(const s16x8*)&lds[32768 + (P)*16384 + boff + (2*(NH))*1024 + (KSW)]; \
    bf[1] = *(const s16x8*)&lds[32768 + (P)*16384 + boff + (2*(NH)+1)*1024 + (KSW)]; \
    PRE \
    CFENCE __builtin_amdgcn_s_barrier(); CFENCE \
    __builtin_amdgcn_s_setprio(1); \
    _Pragma("unroll") \
    for (int m_ = 0; m_ < 8; ++m_){ \
      acc[m_][2*(NH)]   = __builtin_amdgcn_mfma_f32_16x16x32_bf16(af[m_], bf[0], acc[m_][2*(NH)],   0, 0, 0); \
      acc[m_][2*(NH)+1] = __builtin_amdgcn_mfma_f32_16x16x32_bf16(af[m_], bf[1], acc[m_][2*(NH)+1], 0, 0, 0); \
    } \
    __builtin_amdgcn_s_setprio(0); \
    POST \
    CFENCE __builtin_amdgcn_s_barrier(); CFENCE }

template<int NK, int LDK, int NSRC, int IS_GLU>
__global__ __launch_bounds__(512, 2) void k_gemm8(const u16* __restrict__ Aall,
                                                  const float* __restrict__ Bsrc,
                                                  u16* __restrict__ Out,
                                                  const int* __restrict__ cnt){
  // T1: bijective chunked XCD remap of the flattened block id (nwg % 8 == 0)
  const int gx = gridDim.x, gy = gridDim.y;
  const int o = blockIdx.x + gx * (blockIdx.y + gy * blockIdx.z);
  const int nwg = gx * gy * (int)gridDim.z;
  const int q = nwg >> 3;
  const int w = (o & 7) * q + (o >> 3);
  const int mt = w % gx;
  const int t1 = w / gx;
  const int nt = t1 % gy;
  const int e  = t1 / gy;
  if (mt * 256 >= cnt[e]) return;
  __shared__ __align__(1024) u16 lds[65536];   // 128 KiB
  const u16*   Ap     = Aall + (size_t)e * CAP * LDK + (size_t)mt * 256 * LDK;
  const float* Bsrc_e = Bsrc + (size_t)e * LDK * NSRC;

  const int t = threadIdx.x, wid = t >> 6, l = t & 63;
  const int wm = wid >> 2, wn = wid & 3;
  const int lrow = l & 15, lkhi = l >> 4;
  const int c0 = wid * 2;                      // this wave's 2 A-staging chunks
  const size_t srow_off = (size_t)(l >> 3) * LDK + (size_t)(((l & 7) * 8) ^ ((l >> 3) * 8));
  const int aoff = wm * 8192 + lrow * 64;
  const int boff = (wn >> 1) * 8192 + ((wn & 1) * 64 + lrow) * 64;
  const int sx   = (l & 7) * 8;
  const int ksw0 = (lkhi * 8) ^ sx;
  const int ksw1 = (32 + lkhi * 8) ^ sx;

  // B staging geometry: wave covers k-span 32 (kh) x n-span 32 (nb);
  // thread owns a 4k x 4n block at (kl, nl0) of the 64k x 128n half-tile.
  const int kh  = wid & 1;
  const int nb  = wid >> 1;
  const int kl  = kh * 32 + (l & 7) * 4;
  const int nl0 = nb * 32 + (l >> 3) * 4;
  int colh[2];
  #pragma unroll
  for (int h = 0; h < 2; ++h){
    int rpg = nt * 256 + h * 128 + nl0;        // GLU-reordered B-row id
    colh[h] = IS_GLU ? (((rpg >> 5) & 1) * 2048 + ((rpg >> 6) << 5) + (rpg & 31)) : rpg;
  }

  f32x4 acc[8][4] = {};
  s16x8 af[8], bf[2];
  float4 b0r[4], b1r[4];

  // prologue (matches steady-state issue order: B0f, B1f, A per tile)
  LOADB(b0r, 0, 0)                 // 4
  LOADB(b1r, 1, 0)                 // 4
  STAGE_A(0, 0, 0) STAGE_A(1, 0, 0) // 4 (A(0) -> par0)
  VM8                              // drain B0f(0)
  WRITEB(b0r, 0, 0)
  LOADB(b0r, 0, 1)
  VM8                              // drain B1f(0)
  WRITEB(b1r, 1, 0)
  LOADB(b1r, 1, 1)
  VM8                              // drain A(0)  (left: B0f(1)+B1f(1)=8)
  STAGE_A(0, 1, 1) STAGE_A(1, 1, 1) // A(1) -> par1
  LGKM0                            // drain prologue ds_writes
  CFENCE __builtin_amdgcn_s_barrier(); CFENCE

  #pragma unroll 1
  for (int t2 = 0; t2 < NK / 2; ++t2){
    const int te = 2 * t2;
    const bool nl = (t2 < NK / 2 - 1);
    // ---- tile te (reads par0) ----
    PHASE(0, ksw0, 0,
      { VM8 WRITEB(b0r, 0, 1) if (nl){ LOADB(b0r, 0, te + 2) } }, {})
    PHASE(0, ksw0, 1,
      { if (nl){ VM8 } else { VM4 } WRITEB(b1r, 1, 1) if (nl){ LOADB(b1r, 1, te + 2) } }, {})
    PHASE(0, ksw1, 0, {}, { LGKM0 })
    PHASE(0, ksw1, 1, {},
      { LGKM0
        if (nl){ VM8 STAGE_A(0, te + 2, 0) STAGE_A(1, te + 2, 0) }
        else   { VM0 } })
    // ---- tile te+1 (reads par1) ----
    PHASE(1, ksw0, 0,
      { if (nl){ VM8 WRITEB(b0r, 0, 0) LOADB(b0r, 0, te + 3) } }, {})
    PHASE(1, ksw0, 1,
      { if (nl){ VM8 WRITEB(b1r, 1, 0) LOADB(b1r, 1, te + 3) } }, {})
    PHASE(1, ksw1, 0, {}, { LGKM0 })
    PHASE(1, ksw1, 1, {},
      { LGKM0
        if (nl){ VM8 STAGE_A(0, te + 3, 1) STAGE_A(1, te + 3, 1) } })
  }

  // epilogue
  const int rowb = mt * 256 + wm * 128 + lkhi * 4;
  if (IS_GLU){
    u16* hp = Out + (size_t)e * CAP * FDIM;
    const int colb = (nt * 4 + wn) * 32 + lrow;
    #pragma unroll
    for (int m = 0; m < 8; ++m)
      #pragma unroll
      for (int np = 0; np < 2; ++np)
        #pragma unroll
        for (int r = 0; r < 4; ++r){
          size_t row = (size_t)(rowb + m * 16 + r);
          float a = acc[m][np][r], g = acc[m][np + 2][r];
          hp[row * FDIM + colb + np * 16] = f2b(gelu_t(a) * g);
        }
  } else {
    u16* op = Out + (size_t)e * CAP * HDIM;
    const int colb = nt * 256 + wn * 64 + lrow;
    #pragma unroll
    for (int m = 0; m < 8; ++m)
      #pragma unroll
      for (int n = 0; n < 4; ++n)
        #pragma unroll
        for (int r = 0; r < 4; ++r){
          size_t row = (size_t)(rowb + m * 16 + r);
          op[row * HDIM + colb + n * 16] = f2b(acc[m][n][r]);
        }
  }
}

// ---------------- gather: y[s] = g0*out[slot0] + g1*out[slot1]
__global__ __launch_bounds__(256) void k_gather(const u16* __restrict__ oute,
                                                const int* __restrict__ slot,
                                                const float* __restrict__ gates,
                                                float* __restrict__ y){
  int s = blockIdx.x, t = threadIdx.x;
  int s0 = slot[s], s1 = slot[S_TOK + s];
  float g0 = gates[s], g1 = gates[S_TOK + s];
  float4 r; r.x = r.y = r.z = r.w = 0.f;
  if (s0 >= 0){
    ushort4 v = ((const ushort4*)(oute + (size_t)s0 * HDIM))[t];
    r.x += g0 * b2f(v.x); r.y += g0 * b2f(v.y); r.z += g0 * b2f(v.z); r.w += g0 * b2f(v.w);
  }
  if (s1 >= 0){
    ushort4 v = ((const ushort4*)(oute + (size_t)s1 * HDIM))[t];
    r.x += g1 * b2f(v.x); r.y += g1 * b2f(v.y); r.z += g1 * b2f(v.z); r.w += g1 * b2f(v.w);
  }
  ((float4*)(y + (size_t)s * HDIM))[t] = r;
}

extern "C" void kernel_launch(void* const* d_in, const int* in_sizes, int n_in,
                              void* d_out, int out_size, void* d_ws, size_t ws_size,
                              hipStream_t stream){
  (void)in_sizes; (void)n_in; (void)out_size; (void)ws_size;
  const float* x     = (const float*)d_in[0];   // [8192][1024]
  const float* Wg    = (const float*)d_in[1];   // [1024][8]
  const float* W_in  = (const float*)d_in[2];   // [8][1024][4096]
  const float* W_out = (const float*)d_in[3];   // [8][2048][1024]
  float* y = (float*)d_out;

  // workspace layout (~130 MB used)
  char* ws = (char*)d_ws;
  u16* Ainp  = (u16*)(ws);                       // [8][2560][1024] bf16 (reused as out_e)
  u16* hid   = (u16*)(ws + 41943040);            // [8][2560][2048] bf16
  int*   eidx  = (int*)  (ws + 125829120);
  float* vals  = (float*)(ws + 125829120 + 65536);
  int*   slot  = (int*)  (ws + 125829120 + 131072);
  float* gates = (float*)(ws + 125829120 + 196608);
  int*   cnt   = (int*)  (ws + 125829120 + 262144);

  k_gating   <<<dim3(2048), dim3(256),  0, stream>>>(x, Wg, eidx, vals);
  k_scan     <<<dim3(1),    dim3(1024), 0, stream>>>(eidx, vals, slot, gates, cnt);
  k_scatter  <<<dim3(2 * S_TOK), dim3(256), 0, stream>>>(x, slot, Ainp);
  // GEMM1: [2560x1024] @ W_in (f32 [1024][4096], fused cast+transpose) -> GLU -> hid
  k_gemm8<16, 1024, 4096, 1><<<dim3(10, 16, 8), dim3(512), 0, stream>>>(Ainp, W_in, hid, cnt);
  // GEMM2: [2560x2048] @ W_out (f32 [2048][1024], fused cast+transpose) -> out_e
  k_gemm8<32, 2048, 1024, 0><<<dim3(10, 4, 8),  dim3(512), 0, stream>>>(hid, W_out, Ainp, cnt);
  k_gather   <<<dim3(S_TOK), dim3(256), 0, stream>>>(Ainp, slot, gates, y);
}